// Round 5
// baseline (478.199 us; speedup 1.0000x reference)
//
#include <hip/hip_runtime.h>
#include <math.h>

#define NROWS 65536
#define DDIM  64
#define KCODE 4096
#define NSPLIT 4
#define KSPL  (KCODE / NSPLIT)
#define STEPS (KSPL / 16)          // 64
#define SMASK (STEPS - 1)

// output layout (float offsets), concatenated in reference return order
#define O_Q    0           // quantized_st [B,T,D] = 4194304
#define O_LOSS 4194304     // loss scalar
#define O_IDX  4194305     // encoding_indices [B,T] = 65536 (floats)
#define O_NW   4259841     // new_weight [K,D] = 262144
#define O_CS   4521985     // cs [K] = 4096
#define O_NEW  4526081     // new_ema_w [K,D] = 262144

// scratch inside O_Q (dead once vq_gather starts writing Q rows):
//   E_hi : halves [0, 262144)        = floats [0, 131072)
//   E_lo : halves [262144, 524288)   = floats [131072, 262144)
//   A    : floats [262144, 327680)
//   B2   : floats [327680, 331776)
// scratch inside O_NW (clobbered only by vq_final, which runs last):
//   keys : u64[65536] at float offset O_NW+1 (byte-offset %8 == 0)
#define O_A    262144
#define O_B2   327680

typedef _Float16 f16x8 __attribute__((ext_vector_type(8)));
typedef float    f32x4 __attribute__((ext_vector_type(4)));

// ---------------- Kernel A: init + splits + norms + key init ----------------
__global__ __launch_bounds__(256)
void vq_prep(const float* __restrict__ x, const float* __restrict__ w,
             const float* __restrict__ ema_w, float* __restrict__ out,
             unsigned long long* __restrict__ keys,
             double* __restrict__ loss_acc) {
    int i = blockIdx.x * 256 + threadIdx.x;   // grid = 262144 threads exactly
    // table split + EMA init (coalesced, all threads)
    {
        out[O_NEW + i] = 0.99f * ema_w[i];
        float E = w[i] * 4096.0f;             // scaled f16 split of codes
        _Float16 h = (_Float16)E;
        float r = E - (float)h;
        _Float16 lo = (_Float16)(r * 4096.0f);
        ((_Float16*)out)[i] = h;
        ((_Float16*)out)[262144 + i] = lo;
    }
    if (i < NROWS) keys[i] = 0xFFFFFFFFFFFFFFFFULL;
    // x-norms: thread 4r handles row r (EXACT same per-row summation order
    // as validated rounds)
    if ((i & 3) == 0) {
        const int row = i >> 2;               // 0..65535
        const float4* xr = (const float4*)(x + (size_t)row * DDIM);
        float ax = 0.f, ay = 0.f, az = 0.f, aw = 0.f;
        #pragma unroll
        for (int j = 0; j < 16; ++j) {
            float4 v = xr[j];
            ax += v.x * v.x; ay += v.y * v.y; az += v.z * v.z; aw += v.w * v.w;
        }
        out[O_A + row] = (ax + ay) + (az + aw);
    }
    // w-norms: thread 64k handles code k; also zero the count slot
    if ((i & 63) == 0) {
        const int k = i >> 6;                 // 0..4095
        out[O_CS + k] = 0.0f;
        const float4* wr = (const float4*)(w + (size_t)k * DDIM);
        float ax = 0.f, ay = 0.f, az = 0.f, aw = 0.f;
        #pragma unroll
        for (int j = 0; j < 16; ++j) {
            float4 v = wr[j];
            ax += v.x * v.x; ay += v.y * v.y; az += v.z * v.z; aw += v.w * v.w;
        }
        out[O_B2 + k] = (ax + ay) + (az + aw);
    }
    if (i == 0) *loss_acc = 0.0;
}

__device__ inline void split8(float4 a, float4 b, f16x8& hi, f16x8& lo) {
    float vv[8] = {a.x, a.y, a.z, a.w, b.x, b.y, b.z, b.w};
    #pragma unroll
    for (int j = 0; j < 8; ++j) {
        float X = vv[j] * 256.0f;           // x*2^8
        _Float16 h = (_Float16)X;
        float r = X - (float)h;             // exact (Sterbenz)
        hi[j] = h;
        lo[j] = (_Float16)(r * 4096.0f);    // residual*2^12
    }
}

// ---------------- Kernel B: MFMA fused score + argmin (split-K=4, atomic key merge) ----------------
// grid (512, 4) x 256 thr (4 waves) = 2048 blocks -> ~6-8 blocks/CU resident
// (occupancy was the round-4 limiter: 4 blocks/CU, 45% idle issue slots).
// Wave owns 32 rows; scans KSPL=1024 codes in 64 steps of 16. Results merge
// globally via atomicMin on u64 (score-bits<<32 | idx): monotone for the
// all-positive scores, exact lowest-index tie-break.
__global__ __launch_bounds__(256, 3)
void vq_argmin_mfma(const float* __restrict__ x,
                    const _Float16* __restrict__ ehi,
                    const _Float16* __restrict__ elo,
                    const float* __restrict__ Ag,
                    const float* __restrict__ b2g,
                    unsigned long long* __restrict__ keys) {
    __shared__ __align__(16) float b2sh[KSPL];
    const int tid = threadIdx.x;
    const int k0  = blockIdx.y * KSPL;
    ((float4*)b2sh)[tid] = ((const float4*)(b2g + k0))[tid];
    __syncthreads();

    const int l   = tid & 63;
    const int w   = tid >> 6;
    const int g   = l >> 4;        // k-group (0..3)
    const int c16 = l & 15;        // A: row within tile / B: code within tile
    const int rowbase = blockIdx.x * 128 + w * 32;
    const int soff = blockIdx.x & SMASK;   // de-correlate block scan phases

    // A-operand fragments for 2 row-subtiles: rows rowbase + r*16 + c16
    f16x8 xh[2][2], xl[2][2];
    #pragma unroll
    for (int r = 0; r < 2; ++r) {
        const float* xr = x + (size_t)(rowbase + r * 16 + c16) * DDIM + g * 8;
        float4 a0 = *(const float4*)(xr);
        float4 a1 = *(const float4*)(xr + 4);
        float4 a2 = *(const float4*)(xr + 32);
        float4 a3 = *(const float4*)(xr + 36);
        split8(a0, a1, xh[r][0], xl[r][0]);
        split8(a2, a3, xh[r][1], xl[r][1]);
    }
    // per-lane epilogue rows: r*16 + 4*g + v  (C/D: col=lane&15, row=(lane>>4)*4+v)
    float A_reg[2][4];
    #pragma unroll
    for (int r = 0; r < 2; ++r)
        #pragma unroll
        for (int v = 0; v < 4; ++v)
            A_reg[r][v] = Ag[rowbase + r * 16 + 4 * g + v];

    float bestv[2][4]; int bidx[2][4];
    #pragma unroll
    for (int r = 0; r < 2; ++r)
        #pragma unroll
        for (int v = 0; v < 4; ++v) { bestv[r][v] = INFINITY; bidx[r][v] = 0x7FFFFFFF; }

    const _Float16* pbh = ehi + (size_t)(k0 + c16) * DDIM + g * 8;
    const _Float16* pbl = elo + (size_t)(k0 + c16) * DDIM + g * 8;

    f16x8 bh0[2], bh1[2], bl0[2], bl1[2];
    float b2r[2];

#define LOADB(sl, stv) do {                                  \
        const size_t _o = (size_t)(stv) * 1024;              \
        bh0[sl] = *(const f16x8*)(pbh + _o);                 \
        bh1[sl] = *(const f16x8*)(pbh + _o + 32);            \
        bl0[sl] = *(const f16x8*)(pbl + _o);                 \
        bl1[sl] = *(const f16x8*)(pbl + _o + 32);            \
        b2r[sl] = b2sh[(stv) * 16 + c16];                    \
    } while (0)

#define COMP(sl, stv) do {                                                        \
        f32x4 acc1[2], acc2[2];                                                   \
        _Pragma("unroll")                                                         \
        for (int r = 0; r < 2; ++r) {                                             \
            acc1[r] = (f32x4){0.f, 0.f, 0.f, 0.f};                                \
            acc2[r] = (f32x4){0.f, 0.f, 0.f, 0.f};                                \
            acc1[r] = __builtin_amdgcn_mfma_f32_16x16x32_f16(xh[r][0], bh0[sl], acc1[r], 0, 0, 0); \
            acc1[r] = __builtin_amdgcn_mfma_f32_16x16x32_f16(xh[r][1], bh1[sl], acc1[r], 0, 0, 0); \
            acc2[r] = __builtin_amdgcn_mfma_f32_16x16x32_f16(xl[r][0], bh0[sl], acc2[r], 0, 0, 0); \
            acc2[r] = __builtin_amdgcn_mfma_f32_16x16x32_f16(xl[r][1], bh1[sl], acc2[r], 0, 0, 0); \
            acc2[r] = __builtin_amdgcn_mfma_f32_16x16x32_f16(xh[r][0], bl0[sl], acc2[r], 0, 0, 0); \
            acc2[r] = __builtin_amdgcn_mfma_f32_16x16x32_f16(xh[r][1], bl1[sl], acc2[r], 0, 0, 0); \
        }                                                                         \
        const int _c = k0 + (stv) * 16 + c16;                                     \
        _Pragma("unroll")                                                         \
        for (int r = 0; r < 2; ++r) {                                             \
            _Pragma("unroll")                                                     \
            for (int v = 0; v < 4; ++v) {                                         \
                float dotc = fmaf(acc2[r][v], 0x1p-12f, acc1[r][v]);              \
                float t = A_reg[r][v] + b2r[sl];                                  \
                float sc = fmaf(dotc, -0x1p-19f, t);                              \
                if (sc < bestv[r][v] ||                                           \
                    (sc == bestv[r][v] && _c < bidx[r][v])) {                     \
                    bestv[r][v] = sc; bidx[r][v] = _c;                            \
                }                                                                 \
            }                                                                     \
        }                                                                         \
    } while (0)

    { const int st = soff & SMASK;       LOADB(0, st); }
    { const int st = (soff + 1) & SMASK; LOADB(1, st); }

    #pragma unroll 1
    for (int s = 0; s < STEPS; s += 2) {
        { const int st = (soff + s) & SMASK;     COMP(0, st); }
        { const int st = (soff + s + 2) & SMASK; LOADB(0, st); }   // wrap: dead loads at end
        { const int st = (soff + s + 1) & SMASK; COMP(1, st); }
        { const int st = (soff + s + 3) & SMASK; LOADB(1, st); }
    }
#undef LOADB
#undef COMP

    // reduce (value, then lowest index) across the 16 lanes of each k-group
    #pragma unroll
    for (int off = 1; off < 16; off <<= 1) {
        #pragma unroll
        for (int r = 0; r < 2; ++r)
            #pragma unroll
            for (int v = 0; v < 4; ++v) {
                float ob = __shfl_xor(bestv[r][v], off);
                int   oi = __shfl_xor(bidx[r][v], off);
                if (ob < bestv[r][v] || (ob == bestv[r][v] && oi < bidx[r][v])) {
                    bestv[r][v] = ob; bidx[r][v] = oi;
                }
            }
    }
    if (c16 == 0) {
        #pragma unroll
        for (int r = 0; r < 2; ++r)
            #pragma unroll
            for (int v = 0; v < 4; ++v) {
                const int row = rowbase + r * 16 + 4 * g + v;
                // monotone key: positive-float bits then index; atomicMin is
                // exactly (min score, lowest index on exact tie)
                unsigned long long key =
                    ((unsigned long long)__float_as_uint(bestv[r][v]) << 32) |
                    (unsigned)bidx[r][v];
                atomicMin(&keys[row], key);
            }
    }
}

// ---------------- Kernel C: gather + ST output + dw/count atomics + loss ----------------
__global__ __launch_bounds__(256)
void vq_gather(const float* __restrict__ x, const float* __restrict__ w,
               const unsigned long long* __restrict__ keys,
               float* __restrict__ out, double* __restrict__ loss_acc) {
    const int tid = threadIdx.x;
    const int l16 = tid & 15;
    const int row = blockIdx.x * 16 + (tid >> 4);
    const int k = (int)(unsigned)(keys[row] & 0xFFFFFFFFu);
    if (l16 == 0) out[O_IDX + row] = (float)k;

    const float4 w4 = ((const float4*)(w + (size_t)k * DDIM))[l16];
    const float4 x4 = ((const float4*)(x + (size_t)row * DDIM))[l16];
    float4 o;
    o.x = x4.x + (w4.x - x4.x);
    o.y = x4.y + (w4.y - x4.y);
    o.z = x4.z + (w4.z - x4.z);
    o.w = x4.w + (w4.w - x4.w);
    ((float4*)(out + O_Q + (size_t)row * DDIM))[l16] = o;
    float* dwp = out + O_NEW + (size_t)k * DDIM + l16 * 4;
    atomicAdd(dwp + 0, 0.01f * x4.x);
    atomicAdd(dwp + 1, 0.01f * x4.y);
    atomicAdd(dwp + 2, 0.01f * x4.z);
    atomicAdd(dwp + 3, 0.01f * x4.w);
    if (l16 == 0) atomicAdd(out + O_CS + k, 1.0f);
    float dx = w4.x - x4.x, dy = w4.y - x4.y, dz = w4.z - x4.z, dw_ = w4.w - x4.w;
    float e = dx * dx + dy * dy + dz * dz + dw_ * dw_;
    #pragma unroll
    for (int off = 32; off > 0; off >>= 1) e += __shfl_down(e, off);
    if ((tid & 63) == 0) atomicAdd(loss_acc, (double)e);
}

// ---------------- Kernel D: Laplace smoothing + loss write ----------------
__global__ __launch_bounds__(1024)
void vq_cs(const float* __restrict__ ecs, float* __restrict__ out,
           const double* __restrict__ loss_acc) {
    __shared__ float red[1024];
    const int tid = threadIdx.x;
    float cs[4];
    float local = 0.f;
    #pragma unroll
    for (int j = 0; j < 4; ++j) {
        int k = j * 1024 + tid;
        float cnt = out[O_CS + k];
        cs[j] = ecs[k] * 0.99f + 0.01f * cnt;
        local += cs[j];
    }
    red[tid] = local;
    for (int s = 512; s > 0; s >>= 1) {
        __syncthreads();
        if (tid < s) red[tid] += red[tid + s];
    }
    __syncthreads();
    const float n = red[0];
    const float denom = n + 0.04096f;
    #pragma unroll
    for (int j = 0; j < 4; ++j) {
        int k = j * 1024 + tid;
        out[O_CS + k] = (cs[j] + 1e-5f) / denom * n;
    }
    if (tid == 0) out[O_LOSS] = 1.25f * (float)(*loss_acc / 4194304.0);
}

// ---------------- Kernel E: new_weight = new_ema_w / cs ----------------
__global__ __launch_bounds__(256)
void vq_final(float* __restrict__ out) {
    int i = blockIdx.x * 256 + threadIdx.x;
    if (i >= KCODE * DDIM) return;
    int k = i >> 6;
    out[O_NW + i] = out[O_NEW + i] / out[O_CS + k];
}

extern "C" void kernel_launch(void* const* d_in, const int* in_sizes, int n_in,
                              void* d_out, int out_size, void* d_ws, size_t ws_size,
                              hipStream_t stream) {
    (void)in_sizes; (void)n_in; (void)out_size; (void)ws_size;
    const float* x    = (const float*)d_in[0];
    const float* w    = (const float*)d_in[1];
    const float* ecs  = (const float*)d_in[2];
    const float* emaw = (const float*)d_in[3];
    float* out = (float*)d_out;
    double* lacc = (double*)d_ws;

    const _Float16* ehi = (const _Float16*)out;            // halves [0, 262144)
    const _Float16* elo = ((const _Float16*)out) + 262144; // halves [262144, 524288)
    const float*    Ag  = out + O_A;
    // keys: u64[65536] inside O_NW (8B-aligned at +1); dead until vq_final
    unsigned long long* keys = (unsigned long long*)(out + O_NW + 1);

    vq_prep       <<<1024, 256, 0, stream>>>(x, w, emaw, out, keys, lacc);
    vq_argmin_mfma<<<dim3(512, NSPLIT), 256, 0, stream>>>(x, ehi, elo, Ag,
                                                          out + O_B2, keys);
    vq_gather     <<<4096, 256, 0, stream>>>(x, w, keys, out, lacc);
    vq_cs         <<<1, 1024, 0, stream>>>(ecs, out, lacc);
    vq_final      <<<1024, 256, 0, stream>>>(out);
}

// Round 6
// 359.516 us; speedup vs baseline: 1.3301x; 1.3301x over previous
//
#include <hip/hip_runtime.h>
#include <math.h>

#define NROWS 65536
#define DDIM  64
#define KCODE 4096
#define NSPLIT 4
#define KSPL  (KCODE / NSPLIT)
#define STEPS (KSPL / 16)          // 64
#define SMASK (STEPS - 1)

// output layout (float offsets), concatenated in reference return order
#define O_Q    0           // quantized_st [B,T,D] = 4194304
#define O_LOSS 4194304     // loss scalar
#define O_IDX  4194305     // encoding_indices [B,T] = 65536 (floats)
#define O_NW   4259841     // new_weight [K,D] = 262144
#define O_CS   4521985     // cs [K] = 4096
#define O_NEW  4526081     // new_ema_w [K,D] = 262144

// scratch inside O_Q (dead once vq_gather starts writing Q rows):
//   E_hi : halves [0, 262144)  in MFMA-fragment tile order (see vq_prep)
//   E_lo : halves [262144, 524288)
//   A    : floats [262144, 327680)
//   B2   : floats [327680, 331776)
// scratch inside O_NW (clobbered only by vq_final, which runs last):
//   keys : u64[65536] at float offset O_NW+1 (byte-offset %8 == 0)
#define O_A    262144
#define O_B2   327680

typedef _Float16 f16x8 __attribute__((ext_vector_type(8)));
typedef float    f32x4 __attribute__((ext_vector_type(4)));

// ---------------- Kernel A: init + splits + norms + key init ----------------
__global__ __launch_bounds__(256)
void vq_prep(const float* __restrict__ x, const float* __restrict__ w,
             const float* __restrict__ ema_w, float* __restrict__ out,
             unsigned long long* __restrict__ keys,
             double* __restrict__ loss_acc) {
    int i = blockIdx.x * 256 + threadIdx.x;   // grid = 262144 threads exactly
    // table split + EMA init. ehi/elo stored in MFMA-fragment tile order so
    // that argmin's per-step loads are lane-contiguous 1KB bursts:
    //   k = code, j = half index; tile = k>>4
    //   pos = tile*1024 + (j>>5)*512 + ((j>>3)&3)*128 + (k&15)*8 + (j&7)
    // (lane l = g*16+c16 reads f16x8 at tile*1024 + ks*512 + l*8 — the lane
    //  register contents are IDENTICAL to the validated row-major scheme)
    {
        out[O_NEW + i] = 0.99f * ema_w[i];
        const int k = i >> 6, j = i & 63;
        float E = w[i] * 4096.0f;             // scaled f16 split of codes
        _Float16 h = (_Float16)E;
        float r = E - (float)h;
        _Float16 lo = (_Float16)(r * 4096.0f);
        const size_t pos = (size_t)(k >> 4) * 1024 + (size_t)(j >> 5) * 512
                         + (size_t)((j >> 3) & 3) * 128 + (size_t)(k & 15) * 8
                         + (size_t)(j & 7);
        ((_Float16*)out)[pos] = h;
        ((_Float16*)out)[262144 + pos] = lo;
    }
    if (i < NROWS) keys[i] = 0xFFFFFFFFFFFFFFFFULL;
    // x-norms: thread 4r handles row r (EXACT same per-row summation order
    // as validated rounds)
    if ((i & 3) == 0) {
        const int row = i >> 2;               // 0..65535
        const float4* xr = (const float4*)(x + (size_t)row * DDIM);
        float ax = 0.f, ay = 0.f, az = 0.f, aw = 0.f;
        #pragma unroll
        for (int j = 0; j < 16; ++j) {
            float4 v = xr[j];
            ax += v.x * v.x; ay += v.y * v.y; az += v.z * v.z; aw += v.w * v.w;
        }
        out[O_A + row] = (ax + ay) + (az + aw);
    }
    // w-norms: thread 64k handles code k; also zero the count slot
    if ((i & 63) == 0) {
        const int k = i >> 6;                 // 0..4095
        out[O_CS + k] = 0.0f;
        const float4* wr = (const float4*)(w + (size_t)k * DDIM);
        float ax = 0.f, ay = 0.f, az = 0.f, aw = 0.f;
        #pragma unroll
        for (int j = 0; j < 16; ++j) {
            float4 v = wr[j];
            ax += v.x * v.x; ay += v.y * v.y; az += v.z * v.z; aw += v.w * v.w;
        }
        out[O_B2 + k] = (ax + ay) + (az + aw);
    }
    if (i == 0) *loss_acc = 0.0;
}

__device__ inline void split8(float4 a, float4 b, f16x8& hi, f16x8& lo) {
    float vv[8] = {a.x, a.y, a.z, a.w, b.x, b.y, b.z, b.w};
    #pragma unroll
    for (int j = 0; j < 8; ++j) {
        float X = vv[j] * 256.0f;           // x*2^8
        _Float16 h = (_Float16)X;
        float r = X - (float)h;             // exact (Sterbenz)
        hi[j] = h;
        lo[j] = (_Float16)(r * 4096.0f);    // residual*2^12
    }
}

// ---------------- Kernel B: MFMA fused score + argmin (split-K=4, atomic key merge) ----------------
// grid (512, 4) x 256 thr (4 waves). Wave owns 32 rows; scans KSPL=1024 codes
// in 64 steps of 16. B-tables are in fragment order: per step each of the 4
// loads is a lane-contiguous 1KB burst (round-5 fix: the old stride-128B
// gathers serialized in the VMEM path at ~290cyc each and bounded the kernel).
__global__ __launch_bounds__(256, 3)
void vq_argmin_mfma(const float* __restrict__ x,
                    const _Float16* __restrict__ ehi,
                    const _Float16* __restrict__ elo,
                    const float* __restrict__ Ag,
                    const float* __restrict__ b2g,
                    unsigned long long* __restrict__ keys) {
    __shared__ __align__(16) float b2sh[KSPL];
    const int tid = threadIdx.x;
    const int k0  = blockIdx.y * KSPL;
    ((float4*)b2sh)[tid] = ((const float4*)(b2g + k0))[tid];
    __syncthreads();

    const int l   = tid & 63;
    const int w   = tid >> 6;
    const int g   = l >> 4;        // k-group (0..3)
    const int c16 = l & 15;        // A: row within tile / B: code within tile
    const int rowbase = blockIdx.x * 128 + w * 32;
    const int soff = blockIdx.x & SMASK;   // de-correlate block scan phases

    // A-operand fragments for 2 row-subtiles: rows rowbase + r*16 + c16
    f16x8 xh[2][2], xl[2][2];
    #pragma unroll
    for (int r = 0; r < 2; ++r) {
        const float* xr = x + (size_t)(rowbase + r * 16 + c16) * DDIM + g * 8;
        float4 a0 = *(const float4*)(xr);
        float4 a1 = *(const float4*)(xr + 4);
        float4 a2 = *(const float4*)(xr + 32);
        float4 a3 = *(const float4*)(xr + 36);
        split8(a0, a1, xh[r][0], xl[r][0]);
        split8(a2, a3, xh[r][1], xl[r][1]);
    }
    // per-lane epilogue rows: r*16 + 4*g + v  (C/D: col=lane&15, row=(lane>>4)*4+v)
    float A_reg[2][4];
    #pragma unroll
    for (int r = 0; r < 2; ++r)
        #pragma unroll
        for (int v = 0; v < 4; ++v)
            A_reg[r][v] = Ag[rowbase + r * 16 + 4 * g + v];

    float bestv[2][4]; int bidx[2][4];
    #pragma unroll
    for (int r = 0; r < 2; ++r)
        #pragma unroll
        for (int v = 0; v < 4; ++v) { bestv[r][v] = INFINITY; bidx[r][v] = 0x7FFFFFFF; }

    // fragment-order tables: lane l's data for tile t at t*1024 + ks*512 + l*8
    const _Float16* pbh = ehi + (size_t)(k0 >> 4) * 1024 + (size_t)l * 8;
    const _Float16* pbl = elo + (size_t)(k0 >> 4) * 1024 + (size_t)l * 8;

    f16x8 bh0[2], bh1[2], bl0[2], bl1[2];
    float b2r[2];

#define LOADB(sl, stv) do {                                  \
        const size_t _o = (size_t)(stv) * 1024;              \
        bh0[sl] = *(const f16x8*)(pbh + _o);                 \
        bh1[sl] = *(const f16x8*)(pbh + _o + 512);           \
        bl0[sl] = *(const f16x8*)(pbl + _o);                 \
        bl1[sl] = *(const f16x8*)(pbl + _o + 512);           \
        b2r[sl] = b2sh[(stv) * 16 + c16];                    \
    } while (0)

#define COMP(sl, stv) do {                                                        \
        f32x4 acc1[2], acc2[2];                                                   \
        _Pragma("unroll")                                                         \
        for (int r = 0; r < 2; ++r) {                                             \
            acc1[r] = (f32x4){0.f, 0.f, 0.f, 0.f};                                \
            acc2[r] = (f32x4){0.f, 0.f, 0.f, 0.f};                                \
            acc1[r] = __builtin_amdgcn_mfma_f32_16x16x32_f16(xh[r][0], bh0[sl], acc1[r], 0, 0, 0); \
            acc1[r] = __builtin_amdgcn_mfma_f32_16x16x32_f16(xh[r][1], bh1[sl], acc1[r], 0, 0, 0); \
            acc2[r] = __builtin_amdgcn_mfma_f32_16x16x32_f16(xl[r][0], bh0[sl], acc2[r], 0, 0, 0); \
            acc2[r] = __builtin_amdgcn_mfma_f32_16x16x32_f16(xl[r][1], bh1[sl], acc2[r], 0, 0, 0); \
            acc2[r] = __builtin_amdgcn_mfma_f32_16x16x32_f16(xh[r][0], bl0[sl], acc2[r], 0, 0, 0); \
            acc2[r] = __builtin_amdgcn_mfma_f32_16x16x32_f16(xh[r][1], bl1[sl], acc2[r], 0, 0, 0); \
        }                                                                         \
        const int _c = k0 + (stv) * 16 + c16;                                     \
        _Pragma("unroll")                                                         \
        for (int r = 0; r < 2; ++r) {                                             \
            _Pragma("unroll")                                                     \
            for (int v = 0; v < 4; ++v) {                                         \
                float dotc = fmaf(acc2[r][v], 0x1p-12f, acc1[r][v]);              \
                float t = A_reg[r][v] + b2r[sl];                                  \
                float sc = fmaf(dotc, -0x1p-19f, t);                              \
                if (sc < bestv[r][v] ||                                           \
                    (sc == bestv[r][v] && _c < bidx[r][v])) {                     \
                    bestv[r][v] = sc; bidx[r][v] = _c;                            \
                }                                                                 \
            }                                                                     \
        }                                                                         \
    } while (0)

    { const int st = soff & SMASK;       LOADB(0, st); }
    { const int st = (soff + 1) & SMASK; LOADB(1, st); }

    #pragma unroll 1
    for (int s = 0; s < STEPS; s += 2) {
        { const int st = (soff + s) & SMASK;     COMP(0, st); }
        { const int st = (soff + s + 2) & SMASK; LOADB(0, st); }   // wrap: dead loads at end
        { const int st = (soff + s + 1) & SMASK; COMP(1, st); }
        { const int st = (soff + s + 3) & SMASK; LOADB(1, st); }
    }
#undef LOADB
#undef COMP

    // reduce (value, then lowest index) across the 16 lanes of each k-group
    #pragma unroll
    for (int off = 1; off < 16; off <<= 1) {
        #pragma unroll
        for (int r = 0; r < 2; ++r)
            #pragma unroll
            for (int v = 0; v < 4; ++v) {
                float ob = __shfl_xor(bestv[r][v], off);
                int   oi = __shfl_xor(bidx[r][v], off);
                if (ob < bestv[r][v] || (ob == bestv[r][v] && oi < bidx[r][v])) {
                    bestv[r][v] = ob; bidx[r][v] = oi;
                }
            }
    }
    if (c16 == 0) {
        #pragma unroll
        for (int r = 0; r < 2; ++r)
            #pragma unroll
            for (int v = 0; v < 4; ++v) {
                const int row = rowbase + r * 16 + 4 * g + v;
                // monotone key: positive-float bits then index; atomicMin is
                // exactly (min score, lowest index on exact tie)
                unsigned long long key =
                    ((unsigned long long)__float_as_uint(bestv[r][v]) << 32) |
                    (unsigned)bidx[r][v];
                atomicMin(&keys[row], key);
            }
    }
}

// ---------------- Kernel C: gather + ST output + dw/count atomics + loss ----------------
__global__ __launch_bounds__(256)
void vq_gather(const float* __restrict__ x, const float* __restrict__ w,
               const unsigned long long* __restrict__ keys,
               float* __restrict__ out, double* __restrict__ loss_acc) {
    const int tid = threadIdx.x;
    const int l16 = tid & 15;
    const int row = blockIdx.x * 16 + (tid >> 4);
    const int k = (int)(unsigned)(keys[row] & 0xFFFFFFFFu);
    if (l16 == 0) out[O_IDX + row] = (float)k;

    const float4 w4 = ((const float4*)(w + (size_t)k * DDIM))[l16];
    const float4 x4 = ((const float4*)(x + (size_t)row * DDIM))[l16];
    float4 o;
    o.x = x4.x + (w4.x - x4.x);
    o.y = x4.y + (w4.y - x4.y);
    o.z = x4.z + (w4.z - x4.z);
    o.w = x4.w + (w4.w - x4.w);
    ((float4*)(out + O_Q + (size_t)row * DDIM))[l16] = o;
    float* dwp = out + O_NEW + (size_t)k * DDIM + l16 * 4;
    atomicAdd(dwp + 0, 0.01f * x4.x);
    atomicAdd(dwp + 1, 0.01f * x4.y);
    atomicAdd(dwp + 2, 0.01f * x4.z);
    atomicAdd(dwp + 3, 0.01f * x4.w);
    if (l16 == 0) atomicAdd(out + O_CS + k, 1.0f);
    float dx = w4.x - x4.x, dy = w4.y - x4.y, dz = w4.z - x4.z, dw_ = w4.w - x4.w;
    float e = dx * dx + dy * dy + dz * dz + dw_ * dw_;
    #pragma unroll
    for (int off = 32; off > 0; off >>= 1) e += __shfl_down(e, off);
    if ((tid & 63) == 0) atomicAdd(loss_acc, (double)e);
}

// ---------------- Kernel D: Laplace smoothing + loss write ----------------
__global__ __launch_bounds__(1024)
void vq_cs(const float* __restrict__ ecs, float* __restrict__ out,
           const double* __restrict__ loss_acc) {
    __shared__ float red[1024];
    const int tid = threadIdx.x;
    float cs[4];
    float local = 0.f;
    #pragma unroll
    for (int j = 0; j < 4; ++j) {
        int k = j * 1024 + tid;
        float cnt = out[O_CS + k];
        cs[j] = ecs[k] * 0.99f + 0.01f * cnt;
        local += cs[j];
    }
    red[tid] = local;
    for (int s = 512; s > 0; s >>= 1) {
        __syncthreads();
        if (tid < s) red[tid] += red[tid + s];
    }
    __syncthreads();
    const float n = red[0];
    const float denom = n + 0.04096f;
    #pragma unroll
    for (int j = 0; j < 4; ++j) {
        int k = j * 1024 + tid;
        out[O_CS + k] = (cs[j] + 1e-5f) / denom * n;
    }
    if (tid == 0) out[O_LOSS] = 1.25f * (float)(*loss_acc / 4194304.0);
}

// ---------------- Kernel E: new_weight = new_ema_w / cs ----------------
__global__ __launch_bounds__(256)
void vq_final(float* __restrict__ out) {
    int i = blockIdx.x * 256 + threadIdx.x;
    if (i >= KCODE * DDIM) return;
    int k = i >> 6;
    out[O_NW + i] = out[O_NEW + i] / out[O_CS + k];
}

extern "C" void kernel_launch(void* const* d_in, const int* in_sizes, int n_in,
                              void* d_out, int out_size, void* d_ws, size_t ws_size,
                              hipStream_t stream) {
    (void)in_sizes; (void)n_in; (void)out_size; (void)ws_size;
    const float* x    = (const float*)d_in[0];
    const float* w    = (const float*)d_in[1];
    const float* ecs  = (const float*)d_in[2];
    const float* emaw = (const float*)d_in[3];
    float* out = (float*)d_out;
    double* lacc = (double*)d_ws;

    const _Float16* ehi = (const _Float16*)out;            // halves [0, 262144)
    const _Float16* elo = ((const _Float16*)out) + 262144; // halves [262144, 524288)
    const float*    Ag  = out + O_A;
    // keys: u64[65536] inside O_NW (8B-aligned at +1); dead until vq_final
    unsigned long long* keys = (unsigned long long*)(out + O_NW + 1);

    vq_prep       <<<1024, 256, 0, stream>>>(x, w, emaw, out, keys, lacc);
    vq_argmin_mfma<<<dim3(512, NSPLIT), 256, 0, stream>>>(x, ehi, elo, Ag,
                                                          out + O_B2, keys);
    vq_gather     <<<4096, 256, 0, stream>>>(x, w, keys, out, lacc);
    vq_cs         <<<1, 1024, 0, stream>>>(ecs, out, lacc);
    vq_final      <<<1024, 256, 0, stream>>>(out);
}